// Round 4
// baseline (605.564 us; speedup 1.0000x reference)
//
#include <hip/hip_runtime.h>
#include <hip/hip_bf16.h>

// DynamicMemoryBank: B=64, T=1024, C=256, M=1024 (T==M)
//   cat = [x, softmax(x@mem^T)@mem]           -> d_out[0 : 33554432]
//   gate = sigmoid(silu(cat@w1+b1)@w2+b2)
//   new_memory = mean_b(mem*(1-g) + xmean*g)  -> d_out[33554432 : +262144]
//
// R7: the 128²/4-wave/2-barrier GEMM plateaued at MfmaUtil 24% (R6 124 us) --
// the known ceiling of that structure. Port the proven 256²/8-wave/8-phase
// template (T3+T4+T5): BK=64, double-buffered 128 KB LDS, 4 phases per K-tile
// each {ds_read subtile -> barrier -> lgkmcnt(0) -> setprio -> 16 MFMA ->
// barrier}; tile T(t+2) staged into the live buffer's dead regions (B in
// phase C, A in phase D); ONE counted vmcnt(8) per K-tile -- loads stay in
// flight across ~6 phases, never drained to 0 in the loop.

#define BT 65536    // B*T rows

typedef short bf16x8 __attribute__((ext_vector_type(8)));
typedef float f32x4 __attribute__((ext_vector_type(4)));

__device__ __forceinline__ unsigned short f2bf(float f) {
    unsigned x = __float_as_uint(f);
    unsigned r = (x + 0x7FFFu + ((x >> 16) & 1u)) >> 16;
    return (unsigned short)r;
}
__device__ __forceinline__ float bf2f(unsigned short u) {
    return __uint_as_float(((unsigned)u) << 16);
}

// async global->LDS, 16B per lane; hardware writes lane i at lds_base + i*16B.
__device__ __forceinline__ void async16(const unsigned short* g, unsigned short* l) {
    __builtin_amdgcn_global_load_lds((const __attribute__((address_space(1))) unsigned int*)g,
                                     (__attribute__((address_space(3))) unsigned int*)l,
                                     16, 0, 0);
}

__device__ __forceinline__ f32x4 mfma16(bf16x8 a, bf16x8 b, f32x4 c) {
    return __builtin_amdgcn_mfma_f32_16x16x32_bf16(a, b, c, 0, 0, 0);
}

// ---------------- prep kernels ----------------

// x -> d_out left half (fp32 copy) + cat_bf16 left half. 16384 blocks.
__global__ __launch_bounds__(256) void prep_x(const float* __restrict__ x,
                                              float* __restrict__ cat_out,
                                              unsigned short* __restrict__ cat_b) {
    long tid = (long)blockIdx.x * 256 + threadIdx.x;
    long i4 = tid * 4;
    long row = i4 >> 8;
    int c = (int)(i4 & 255);
    float4 v = *(const float4*)&x[i4];
    *(float4*)&cat_out[row * 512 + c] = v;
    ushort4 b4;
    b4.x = f2bf(v.x); b4.y = f2bf(v.y); b4.z = f2bf(v.z); b4.w = f2bf(v.w);
    *(ushort4*)&cat_b[row * 512 + c] = b4;
}

// memory -> mem_bf16 [m][c] and memT_bf16 [c][m]
__global__ __launch_bounds__(256) void prep_mem(const float* __restrict__ mem,
                                                unsigned short* __restrict__ mem_b,
                                                unsigned short* __restrict__ memT_b) {
    int tid = blockIdx.x * 256 + threadIdx.x;  // 262144
    mem_b[tid] = f2bf(mem[tid]);
    int c = tid >> 10, m = tid & 1023;
    memT_b[tid] = f2bf(mem[m * 256 + c]);
}

// w1[512k][1024f] -> w1T[1024f][512k]
__global__ __launch_bounds__(256) void prep_w1(const float* __restrict__ w1,
                                               unsigned short* __restrict__ w1T) {
    int tid = blockIdx.x * 256 + threadIdx.x;  // 524288
    int f = tid >> 9, k = tid & 511;
    w1T[tid] = f2bf(w1[k * 1024 + f]);
}

// w2[1024k][256c] -> w2T[256c][1024k]
__global__ __launch_bounds__(256) void prep_w2(const float* __restrict__ w2,
                                               unsigned short* __restrict__ w2T) {
    int tid = blockIdx.x * 256 + threadIdx.x;  // 262144
    int c = tid >> 10, k = tid & 1023;
    w2T[tid] = f2bf(w2[k * 256 + c]);
}

// xmean[b][c] = mean_t x[b,t,c]  (xmean zeroed via hipMemsetAsync first)
__global__ __launch_bounds__(256) void xmean_k(const float* __restrict__ x,
                                               float* __restrict__ xmean) {
    int b = blockIdx.x;
    int t0 = blockIdx.y * 64;
    int c = threadIdx.x;
    float s = 0.f;
    for (int t = 0; t < 64; t++)
        s += x[((long)(b * 1024 + t0 + t)) * 256 + c];
    atomicAdd(&xmean[b * 256 + c], s * (1.f / 1024.f));
}

// ---------------- 256x256 8-wave 8-phase bf16 MFMA GEMM ----------------
// C[M x N] = A[M x K] * Bt[N x K]^T, bf16, fp32 accum.
// BM=BN=256, BK=64. 512 threads = 8 waves (2M x 4N), per-wave 128x64 of C:
// acc[8][4] f32x4, 64 MFMA per K-tile per wave.
// LDS: lA/lB[2][256*64] shorts = 128 KB total, 1 block/CU, 2 waves/SIMD.
// Tile rows stored as 8 chunks of 8 bf16; chunk c of row r at slot c^(r&7)
// (pre-swizzled global source) -> frag ds_read_b128 is conflict-free.
// Per K-tile T(t) (buffer t&1), 4 phases:
//   P_A: ds_read A[m0-3]x2k + B[n0-1]x2k (12)          -> MFMA m0-3 x n0-1
//   P_B: ds_read B[n2-3]x2k (4)                        -> MFMA m0-3 x n2-3
//   P_C: ds_read A[m4-7]x2k (8); stage T(t+2).B        -> MFMA m4-7 x n0-1
//   P_D: stage T(t+2).A; s_waitcnt vmcnt(8)            -> MFMA m4-7 x n2-3
// Each phase: {reads/stages; barrier; lgkmcnt(0); setprio(1); 16 MFMA;
// setprio(0); barrier}. Region safety: B of the live buffer is last READ in
// P_B (retired via each wave's lgkmcnt(0) before P_B's end barrier), so
// P_C's DMA writes to it are safe; A last read in P_C -> P_D writes safe.
// vmcnt(8) retires all but T(t+2)'s 8 loads => T(t+1) is resident before its
// group starts. Loads stay in flight across ~6 phases; never drained to 0.
// MODE 0: energy -> bf16 (ld 1024)       MODE 1: retrieved -> fp32+bf16 cat
// MODE 2: silu(acc+b1) -> bf16 (ld 1024) MODE 3: sigmoid(acc+b2) -> fp32 (ld 256)
template <int MODE, int K>
__global__ __launch_bounds__(512, 2) void gemm_bt(const unsigned short* __restrict__ A,
                                                  const unsigned short* __restrict__ Bt,
                                                  float* __restrict__ outF,
                                                  unsigned short* __restrict__ outB,
                                                  const float* __restrict__ bias) {
    constexpr long LDA = (MODE == 0 || MODE == 2) ? 512 : 1024;
    constexpr int NX = (MODE == 0 || MODE == 2) ? 4 : 1;   // n-blocks
    constexpr int NWG = NX * 256;
    constexpr int NT = K / 64;                             // K-tiles (>= 4, even)

    const int t = threadIdx.x;
    const int wave = t >> 6, lane = t & 63;
    const int waveM = wave >> 2, waveN = wave & 3;         // 2 x 4
    const int quad = lane >> 4, l16 = lane & 15;

    // XCD-bijective swizzle (NWG % 8 == 0): each XCD owns a contiguous
    // m-range for all n -> A-panels fetched once, shared in its L2.
    const int lid = blockIdx.y * NX + blockIdx.x;
    const int sid = (lid & 7) * (NWG >> 3) + (lid >> 3);
    const int nb = sid % NX;
    const int mb = sid / NX;
    const long n0 = (long)nb * 256;
    const long m0 = (long)mb * 256;

    __shared__ unsigned short lA[2][256 * 64];
    __shared__ unsigned short lB[2][256 * 64];

    f32x4 acc[8][4] = {};
    bf16x8 aW[4][2], bAll[4][2];

    // ---- staging geometry: per call, thread covers row tid>>3 (of 64),
    // slot tid&7; slot s of row r holds global chunk s^(r&7). ----
    const int srow = t >> 3;                    // 0..63
    const int schk = (t & 7) ^ (srow & 7);
    const unsigned short* aS = A + (m0 + srow) * LDA + schk * 8;
    const unsigned short* bS = Bt + (n0 + srow) * (long)K + schk * 8;

#define STAGE_A(BUF, KT) do { _Pragma("unroll")                               \
        for (int c = 0; c < 4; c++)                                           \
            async16(aS + (long)c * 64 * LDA + (KT) * 64,                      \
                    &lA[BUF][(c * 64 + wave * 8) * 64]); } while (0)
#define STAGE_B(BUF, KT) do { _Pragma("unroll")                               \
        for (int c = 0; c < 4; c++)                                           \
            async16(bS + (long)c * 64 * (long)K + (KT) * 64,                  \
                    &lB[BUF][(c * 64 + wave * 8) * 64]); } while (0)

    // ---- frag ds_read offsets (shorts) ----
    const int sx = l16 & 7;
    const int aBase = (waveM * 128 + l16) * 64;
    const int bBase = (waveN * 64 + l16) * 64;
    const int c0 = ((quad    ) ^ sx) * 8;       // k-sub 0 chunk slot
    const int c1 = ((quad + 4) ^ sx) * 8;       // k-sub 1 chunk slot

#define RD_A(BUF, MLO) do { _Pragma("unroll")                                 \
        for (int m = 0; m < 4; m++) {                                         \
            aW[m][0] = *(const bf16x8*)&lA[BUF][aBase + ((MLO) + m) * 1024 + c0]; \
            aW[m][1] = *(const bf16x8*)&lA[BUF][aBase + ((MLO) + m) * 1024 + c1]; \
        } } while (0)
#define RD_B(BUF, NLO) do { _Pragma("unroll")                                 \
        for (int n = 0; n < 2; n++) {                                         \
            bAll[(NLO) + n][0] = *(const bf16x8*)&lB[BUF][bBase + ((NLO) + n) * 1024 + c0]; \
            bAll[(NLO) + n][1] = *(const bf16x8*)&lB[BUF][bBase + ((NLO) + n) * 1024 + c1]; \
        } } while (0)
#define MM(MLO, NLO) do { _Pragma("unroll")                                   \
        for (int m = 0; m < 4; m++) { _Pragma("unroll")                       \
            for (int n = 0; n < 2; n++) {                                     \
                acc[(MLO)+m][(NLO)+n] = mfma16(aW[m][0], bAll[(NLO)+n][0], acc[(MLO)+m][(NLO)+n]); \
                acc[(MLO)+m][(NLO)+n] = mfma16(aW[m][1], bAll[(NLO)+n][1], acc[(MLO)+m][(NLO)+n]); \
            } } } while (0)

#define PH_IN()  do { __builtin_amdgcn_sched_barrier(0);                      \
        __builtin_amdgcn_s_barrier();                                         \
        asm volatile("s_waitcnt lgkmcnt(0)" ::: "memory");                    \
        __builtin_amdgcn_sched_barrier(0);                                    \
        __builtin_amdgcn_s_setprio(1); } while (0)
#define PH_OUT() do { __builtin_amdgcn_s_setprio(0);                          \
        __builtin_amdgcn_sched_barrier(0);                                    \
        __builtin_amdgcn_s_barrier(); } while (0)

#define GROUP(KT, BUF, DOSTAGE, DOWAIT0) do {                                 \
        /* P_A */                                                             \
        RD_A(BUF, 0); RD_B(BUF, 0);                                           \
        PH_IN(); MM(0, 0); PH_OUT();                                          \
        /* P_B */                                                             \
        RD_B(BUF, 2);                                                         \
        PH_IN(); MM(0, 2); PH_OUT();                                          \
        /* P_C */                                                             \
        RD_A(BUF, 4);                                                         \
        if (DOSTAGE) STAGE_B(BUF, (KT) + 2);                                  \
        PH_IN(); MM(4, 0); PH_OUT();                                          \
        /* P_D */                                                             \
        if (DOSTAGE) {                                                        \
            STAGE_A(BUF, (KT) + 2);                                           \
            asm volatile("s_waitcnt vmcnt(8)" ::: "memory");                  \
        } else if (DOWAIT0) {                                                 \
            asm volatile("s_waitcnt vmcnt(0)" ::: "memory");                  \
        }                                                                     \
        PH_IN(); MM(4, 2); PH_OUT();                                          \
    } while (0)

    // prologue: T0 -> buf0, T1 -> buf1 (16 loads); vmcnt(8) => T0 resident.
    STAGE_A(0, 0); STAGE_B(0, 0);
    STAGE_A(1, 1); STAGE_B(1, 1);
    asm volatile("s_waitcnt vmcnt(8)" ::: "memory");
    __builtin_amdgcn_s_barrier();
    __builtin_amdgcn_sched_barrier(0);

#pragma unroll 1
    for (int kt = 0; kt < NT; kt += 2) {
        GROUP(kt, 0, kt + 2 < NT, kt + 1 < NT);
        GROUP(kt + 1, 1, kt + 3 < NT, kt + 2 < NT);
    }

#undef GROUP
#undef PH_IN
#undef PH_OUT
#undef MM
#undef RD_A
#undef RD_B
#undef STAGE_A
#undef STAGE_B

    // ---- epilogue: C/D layout row=quad*4+r, col=l16 ----
#pragma unroll
    for (int n = 0; n < 4; n++) {
        long col = n0 + waveN * 64 + n * 16 + l16;
        float bval = (MODE == 2 || MODE == 3) ? bias[col] : 0.f;
#pragma unroll
        for (int m = 0; m < 8; m++) {
#pragma unroll
            for (int r = 0; r < 4; r++) {
                long row = m0 + waveM * 128 + m * 16 + quad * 4 + r;
                float v = acc[m][n][r];
                if (MODE == 0) {
                    outB[row * 1024 + col] = f2bf(v);
                } else if (MODE == 1) {
                    long o = row * 512 + 256 + col;
                    outF[o] = v;
                    outB[o] = f2bf(v);
                } else if (MODE == 2) {
                    float z = v + bval;
                    float s = 1.f / (1.f + __expf(-z));
                    outB[row * 1024 + col] = f2bf(z * s);   // silu
                } else {
                    float z = v + bval;
                    outF[row * 256 + col] = 1.f / (1.f + __expf(-z));  // sigmoid
                }
            }
        }
    }
}

// ---------------- row softmax over M=1024, in place on bf16 P ----------------
__global__ __launch_bounds__(256) void softmax_rows(unsigned short* __restrict__ P) {
    long row = (long)blockIdx.x * 4 + (threadIdx.x >> 6);
    int lane = threadIdx.x & 63;
    unsigned short* p = P + row * 1024 + lane * 16;
    uint4 u0 = *(const uint4*)p;
    uint4 u1 = *(const uint4*)(p + 8);
    const unsigned short* ua = (const unsigned short*)&u0;
    const unsigned short* ub = (const unsigned short*)&u1;
    float v[16];
#pragma unroll
    for (int i = 0; i < 8; i++) { v[i] = bf2f(ua[i]); v[i + 8] = bf2f(ub[i]); }
    float m = -1e30f;
#pragma unroll
    for (int i = 0; i < 16; i++) m = fmaxf(m, v[i]);
    for (int off = 32; off >= 1; off >>= 1) m = fmaxf(m, __shfl_xor(m, off));
    float s = 0.f;
#pragma unroll
    for (int i = 0; i < 16; i++) { v[i] = __expf(v[i] - m); s += v[i]; }
    for (int off = 32; off >= 1; off >>= 1) s += __shfl_xor(s, off);
    float inv = 1.f / s;
    unsigned short o[16];
#pragma unroll
    for (int i = 0; i < 16; i++) o[i] = f2bf(v[i] * inv);
    *(uint4*)p = *(uint4*)&o[0];
    *(uint4*)(p + 8) = *(uint4*)&o[8];
}

// ---------------- final memory blend + batch mean ----------------
// new_memory[m,c] = mem[m,c] + (1/64) * sum_b gate[b,m,c]*(xmean[b,c]-mem[m,c])
__global__ __launch_bounds__(256) void reduce_mem(const float* __restrict__ gate,
                                                  const float* __restrict__ memory,
                                                  const float* __restrict__ xmean,
                                                  float* __restrict__ out2) {
    int m = blockIdx.x, c = threadIdx.x;
    float mm = memory[m * 256 + c];
    float s = 0.f;
    for (int b = 0; b < 64; b++)
        s += gate[((long)(b * 1024 + m)) * 256 + c] * (xmean[b * 256 + c] - mm);
    out2[m * 256 + c] = mm + s * (1.f / 64.f);
}

extern "C" void kernel_launch(void* const* d_in, const int* in_sizes, int n_in,
                              void* d_out, int out_size, void* d_ws, size_t ws_size,
                              hipStream_t stream) {
    const float* x      = (const float*)d_in[0];
    const float* memory = (const float*)d_in[1];
    const float* w1     = (const float*)d_in[2];
    const float* b1     = (const float*)d_in[3];
    const float* w2     = (const float*)d_in[4];
    const float* b2     = (const float*)d_in[5];
    float* out = (float*)d_out;

    // workspace carve (all 16B aligned); peak ~194.6 MiB
    unsigned short* mem_b  = (unsigned short*)d_ws;            // 262144 el
    unsigned short* memT_b = mem_b + 262144;                   // 262144 el
    unsigned short* w1T    = memT_b + 262144;                  // 524288 el
    unsigned short* w2T    = w1T + 524288;                     // 262144 el
    float* xmean           = (float*)(w2T + 262144);           // 16384 el
    unsigned short* cat_b  = (unsigned short*)(xmean + 16384); // BT x 512
    unsigned short* Pbuf   = cat_b + 33554432;                 // BT x 1024; reused as h
    float* gate            = (float*)cat_b;                    // aliases cat_b (dead after GEMM2)

    hipMemsetAsync(xmean, 0, 64 * 256 * sizeof(float), stream);

    prep_mem<<<1024, 256, 0, stream>>>(memory, mem_b, memT_b);
    prep_w1<<<2048, 256, 0, stream>>>(w1, w1T);
    prep_w2<<<1024, 256, 0, stream>>>(w2, w2T);
    prep_x<<<16384, 256, 0, stream>>>(x, out, cat_b);
    xmean_k<<<dim3(64, 16), 256, 0, stream>>>(x, xmean);

    // energy = x @ mem^T : A=cat_b left half (LDA=512, K=256), Bt=mem_b[1024][256]
    gemm_bt<0, 256><<<dim3(4, 256), 512, 0, stream>>>(cat_b, mem_b, nullptr, Pbuf, nullptr);
    softmax_rows<<<16384, 256, 0, stream>>>(Pbuf);
    // retrieved = P @ mem : A=Pbuf (LDA=1024, K=1024), Bt=memT[256][1024]
    gemm_bt<1, 1024><<<dim3(1, 256), 512, 0, stream>>>(Pbuf, memT_b, out, cat_b, nullptr);
    // h = silu(cat@w1+b1) : A=cat_b (LDA=512, K=512), Bt=w1T[1024][512]
    gemm_bt<2, 512><<<dim3(4, 256), 512, 0, stream>>>(cat_b, w1T, nullptr, Pbuf, b1);
    // gate = sigmoid(h@w2+b2) : A=Pbuf/h (LDA=1024, K=1024), Bt=w2T[256][1024]
    gemm_bt<3, 1024><<<dim3(1, 256), 512, 0, stream>>>(Pbuf, w2T, gate, nullptr, b2);

    reduce_mem<<<1024, 256, 0, stream>>>(gate, memory, xmean, out + 33554432);
}

// Round 6
// 575.407 us; speedup vs baseline: 1.0524x; 1.0524x over previous
//
#include <hip/hip_runtime.h>
#include <hip/hip_bf16.h>

// DynamicMemoryBank: B=64, T=1024, C=256, M=1024 (T==M)
//   cat = [x, softmax(x@mem^T)@mem]           -> d_out[0 : 33554432]
//   gate = sigmoid(silu(cat@w1+b1)@w2+b2)
//   new_memory = mean_b(mem*(1-g) + xmean*g)  -> d_out[33554432 : +262144]
//
// R9 = R8 resubmitted verbatim (R8's bench died in container acquisition --
// "MI355X container failed twice", no timing/pass data => infra flake, not a
// kernel verdict; design re-audited for deadlock/OOB, none found).
// R8: (a) GEMMs = R6's proven triple-buffered 128x128 structure.
// (b) fused attn_es = energy GEMM + row softmax in one pass: BM=64 rows x
// full N=1024, S in registers (acc[4][8]); each of 8 waves owns a private
// 128-col strip of mem -> per-wave B staging with own counted vmcnt, ZERO
// barriers in the K-loop; softmax via reg+shfl reduce + 2KB LDS cross-wave
// round. Kills softmax_rows (268 MB HBM) and the separate energy dispatch.

#define BT 65536    // B*T rows

typedef short bf16x8 __attribute__((ext_vector_type(8)));
typedef float f32x4 __attribute__((ext_vector_type(4)));

__device__ __forceinline__ unsigned short f2bf(float f) {
    unsigned x = __float_as_uint(f);
    unsigned r = (x + 0x7FFFu + ((x >> 16) & 1u)) >> 16;
    return (unsigned short)r;
}
__device__ __forceinline__ float bf2f(unsigned short u) {
    return __uint_as_float(((unsigned)u) << 16);
}

// async global->LDS, 16B per lane; hardware writes lane i at lds_base + i*16B.
__device__ __forceinline__ void async16(const unsigned short* g, unsigned short* l) {
    __builtin_amdgcn_global_load_lds((const __attribute__((address_space(1))) unsigned int*)g,
                                     (__attribute__((address_space(3))) unsigned int*)l,
                                     16, 0, 0);
}

__device__ __forceinline__ f32x4 mfma16(bf16x8 a, bf16x8 b, f32x4 c) {
    return __builtin_amdgcn_mfma_f32_16x16x32_bf16(a, b, c, 0, 0, 0);
}

// ---------------- prep kernels ----------------

// x -> d_out left half (fp32 copy) + cat_bf16 left half. 16384 blocks.
__global__ __launch_bounds__(256) void prep_x(const float* __restrict__ x,
                                              float* __restrict__ cat_out,
                                              unsigned short* __restrict__ cat_b) {
    long tid = (long)blockIdx.x * 256 + threadIdx.x;
    long i4 = tid * 4;
    long row = i4 >> 8;
    int c = (int)(i4 & 255);
    float4 v = *(const float4*)&x[i4];
    *(float4*)&cat_out[row * 512 + c] = v;
    ushort4 b4;
    b4.x = f2bf(v.x); b4.y = f2bf(v.y); b4.z = f2bf(v.z); b4.w = f2bf(v.w);
    *(ushort4*)&cat_b[row * 512 + c] = b4;
}

// memory -> mem_bf16 [m][c] and memT_bf16 [c][m]
__global__ __launch_bounds__(256) void prep_mem(const float* __restrict__ mem,
                                                unsigned short* __restrict__ mem_b,
                                                unsigned short* __restrict__ memT_b) {
    int tid = blockIdx.x * 256 + threadIdx.x;  // 262144
    mem_b[tid] = f2bf(mem[tid]);
    int c = tid >> 10, m = tid & 1023;
    memT_b[tid] = f2bf(mem[m * 256 + c]);
}

// w1[512k][1024f] -> w1T[1024f][512k]
__global__ __launch_bounds__(256) void prep_w1(const float* __restrict__ w1,
                                               unsigned short* __restrict__ w1T) {
    int tid = blockIdx.x * 256 + threadIdx.x;  // 524288
    int f = tid >> 9, k = tid & 511;
    w1T[tid] = f2bf(w1[k * 1024 + f]);
}

// w2[1024k][256c] -> w2T[256c][1024k]
__global__ __launch_bounds__(256) void prep_w2(const float* __restrict__ w2,
                                               unsigned short* __restrict__ w2T) {
    int tid = blockIdx.x * 256 + threadIdx.x;  // 262144
    int c = tid >> 10, k = tid & 1023;
    w2T[tid] = f2bf(w2[k * 256 + c]);
}

// xmean[b][c] = mean_t x[b,t,c]  (xmean zeroed via hipMemsetAsync first)
__global__ __launch_bounds__(256) void xmean_k(const float* __restrict__ x,
                                               float* __restrict__ xmean) {
    int b = blockIdx.x;
    int t0 = blockIdx.y * 64;
    int c = threadIdx.x;
    float s = 0.f;
    for (int t = 0; t < 64; t++)
        s += x[((long)(b * 1024 + t0 + t)) * 256 + c];
    atomicAdd(&xmean[b * 256 + c], s * (1.f / 1024.f));
}

// ---------------- fused energy + softmax ----------------
// P[64 rows x 1024] = softmax_row( x_rows[64,256] @ mem[1024,256]^T ), bf16 out.
// 1024 blocks x 512 thr (8 waves). Wave w owns cols [w*128, +128) -> its own
// private B strip: stages mem rows [w*128,+128) x 32k into its LDS region via
// global_load_lds, syncs with its OWN vmcnt -- no barriers in the K-loop.
// A-frags (x rows) stream global->reg (L1 serves each row's 512B across the
// 8 k-steps). acc[4][8] = full 64x128 S-strip per wave in registers.
// Softmax: reg-max over n, shfl_xor over l16, 2KB LDS round over 8 waves
// (lB is dead by then -> overlay). 3 barriers total, all post-compute.
__global__ __launch_bounds__(512, 2) void attn_es(const unsigned short* __restrict__ catb,
                                                  const unsigned short* __restrict__ memB,
                                                  unsigned short* __restrict__ P) {
    const int t = threadIdx.x;
    const int wave = t >> 6, lane = t & 63;
    const int quad = lane >> 4, l16 = lane & 15;
    const long m0 = (long)blockIdx.x * 64;

    __shared__ unsigned short lB[2][32768];   // [buf][1024 rows][32 k-shorts], 128 KB

    f32x4 acc[4][8] = {};                     // [m-frag][n-frag]

    // B staging: lane covers row bRow = w*128 + j*16 + (lane>>2), slot lane&3.
    // Slot s of row r holds global chunk s ^ ((r>>1)&3); (r>>1)&3 is invariant
    // in j (j*16 -> +8 after >>1, = 0 mod 4), so one swizzled base pointer works.
    const int bRow = wave * 128 + (lane >> 2);
    const int bChk = (lane & 3) ^ ((bRow >> 1) & 3);
    const unsigned short* bSrc = memB + (long)bRow * 256 + bChk * 8;

#define STAGE(BUF, KST) do { _Pragma("unroll")                                \
    for (int j = 0; j < 8; j++)                                               \
        async16(bSrc + (long)j * (16 * 256) + (KST) * 32,                     \
                &lB[BUF][(wave * 128 + j * 16) * 32]); } while (0)

    // A-frag pointers: rows m0 + i*16 + l16, k base quad*8 (A[m=l16][k=quad*8+j])
    const unsigned short* Ap[4];
#pragma unroll
    for (int i = 0; i < 4; i++)
        Ap[i] = catb + (m0 + i * 16 + l16) * 512 + quad * 8;

    // B-frag LDS offsets: row = w*128 + n*16 + l16, chunk slot quad^((row>>1)&3)
    // -> banks spread 2-way (free), same scheme R6 measured at 0 conflicts.
    int boff[8];
#pragma unroll
    for (int n = 0; n < 8; n++) {
        int r = wave * 128 + n * 16 + l16;
        boff[n] = r * 32 + ((quad ^ ((r >> 1) & 3)) * 8);
    }

    STAGE(0, 0);
#pragma unroll
    for (int kst = 0; kst < 8; kst++) {
        bf16x8 af[4];
#pragma unroll
        for (int i = 0; i < 4; i++) af[i] = *(const bf16x8*)(Ap[i] + kst * 32);
        __builtin_amdgcn_sched_barrier(0);
        if (kst < 7) STAGE((kst + 1) & 1, kst + 1);
        __builtin_amdgcn_sched_barrier(0);
        // issue order: [A x4][stage-next x8]; vmcnt(8) retires current-B DMAs
        // (oldest) AND the A-frags, leaves next-B's 8 in flight.
        if (kst < 7) asm volatile("s_waitcnt vmcnt(8)" ::: "memory");
        else         asm volatile("s_waitcnt vmcnt(0)" ::: "memory");
        __builtin_amdgcn_sched_barrier(0);
        const unsigned short* bb = &lB[kst & 1][0];
        bf16x8 bfr[8];
#pragma unroll
        for (int n = 0; n < 8; n++) bfr[n] = *(const bf16x8*)&bb[boff[n]];
#pragma unroll
        for (int i = 0; i < 4; i++)
#pragma unroll
            for (int n = 0; n < 8; n++)
                acc[i][n] = mfma16(af[i], bfr[n], acc[i][n]);
    }
#undef STAGE

    // ---- softmax over the 1024 cols of each of the 64 rows ----
    // lane holds rows {m*16+quad*4+r}, cols {w*128+n*16+l16}.
    f32x4 vmax[4];
#pragma unroll
    for (int m = 0; m < 4; m++) {
        f32x4 v = acc[m][0];
#pragma unroll
        for (int n = 1; n < 8; n++)
#pragma unroll
            for (int r = 0; r < 4; r++) v[r] = fmaxf(v[r], acc[m][n][r]);
#pragma unroll
        for (int b = 1; b < 16; b <<= 1)
#pragma unroll
            for (int r = 0; r < 4; r++) v[r] = fmaxf(v[r], __shfl_xor(v[r], b));
        vmax[m] = v;     // wave-partial row max, duplicated over l16
    }
    __syncthreads();                       // all waves done reading lB
    float* red = (float*)&lB[0][0];        // [8 waves][64 rows] max; +512: sums
    if (l16 == 0) {
#pragma unroll
        for (int m = 0; m < 4; m++)
            *(f32x4*)&red[wave * 64 + m * 16 + quad * 4] = vmax[m];
    }
    __syncthreads();
#pragma unroll
    for (int m = 0; m < 4; m++) {
        f32x4 v = *(const f32x4*)&red[m * 16 + quad * 4];
#pragma unroll
        for (int w = 1; w < 8; w++) {
            f32x4 o = *(const f32x4*)&red[w * 64 + m * 16 + quad * 4];
#pragma unroll
            for (int r = 0; r < 4; r++) v[r] = fmaxf(v[r], o[r]);
        }
        vmax[m] = v;                       // global row max
    }
    // exp in place + wave-partial row sums
    f32x4 vsum[4];
    float* red2 = red + 512;
#pragma unroll
    for (int m = 0; m < 4; m++) {
        f32x4 s = {0.f, 0.f, 0.f, 0.f};
#pragma unroll
        for (int n = 0; n < 8; n++)
#pragma unroll
            for (int r = 0; r < 4; r++) {
                float e = __expf(acc[m][n][r] - vmax[m][r]);
                acc[m][n][r] = e;
                s[r] += e;
            }
#pragma unroll
        for (int b = 1; b < 16; b <<= 1)
#pragma unroll
            for (int r = 0; r < 4; r++) s[r] += __shfl_xor(s[r], b);
        vsum[m] = s;
    }
    if (l16 == 0) {
#pragma unroll
        for (int m = 0; m < 4; m++)
            *(f32x4*)&red2[wave * 64 + m * 16 + quad * 4] = vsum[m];
    }
    __syncthreads();
#pragma unroll
    for (int m = 0; m < 4; m++) {
        f32x4 s = *(const f32x4*)&red2[m * 16 + quad * 4];
#pragma unroll
        for (int w = 1; w < 8; w++) {
            f32x4 o = *(const f32x4*)&red2[w * 64 + m * 16 + quad * 4];
#pragma unroll
            for (int r = 0; r < 4; r++) s[r] += o[r];
        }
#pragma unroll
        for (int r = 0; r < 4; r++) vsum[m][r] = 1.f / s[r];
    }
    // write P (bf16), C/D layout row=quad*4+r col=l16
#pragma unroll
    for (int m = 0; m < 4; m++)
#pragma unroll
        for (int n = 0; n < 8; n++) {
            long col = wave * 128 + n * 16 + l16;
#pragma unroll
            for (int r = 0; r < 4; r++) {
                long row = m0 + m * 16 + quad * 4 + r;
                P[row * 1024 + col] = f2bf(acc[m][n][r] * vsum[m][r]);
            }
        }
}

// ---------------- templated bf16 MFMA GEMM (3-stage pipelined, R6) ----------------
// C[M x N] = A[M x K] * Bt[N x K]^T, bf16, fp32 accum.
// BM=BN=128, BK=32. 256 threads = 4 waves 2x2, each wave 64x64 of C.
// Triple-buffered LDS (48 KB); STAGE(kt+2) -> compute(kt) -> vmcnt(4)
// lgkmcnt(0) -> s_barrier. Loads stay in flight across barriers.
// MODE 1: retrieved -> fp32+bf16 cat
// MODE 2: silu(acc+b1) -> bf16 (ld 1024) MODE 3: sigmoid(acc+b2) -> fp32 (ld 256)

__device__ __forceinline__ void compute_tile(const unsigned short* bufA,
                                             const unsigned short* bufB,
                                             const int* aoff, const int* boff,
                                             f32x4 acc[4][4]) {
    bf16x8 af[4], bfr[4];
#pragma unroll
    for (int i = 0; i < 4; i++) af[i] = *(const bf16x8*)&bufA[aoff[i]];
#pragma unroll
    for (int j = 0; j < 4; j++) bfr[j] = *(const bf16x8*)&bufB[boff[j]];
#pragma unroll
    for (int i = 0; i < 4; i++)
#pragma unroll
        for (int j = 0; j < 4; j++)
            acc[i][j] = __builtin_amdgcn_mfma_f32_16x16x32_bf16(af[i], bfr[j], acc[i][j], 0, 0, 0);
}

template <int MODE, int K>
__global__ __launch_bounds__(256) void gemm_bt(const unsigned short* __restrict__ A,
                                               const unsigned short* __restrict__ Bt,
                                               float* __restrict__ outF,
                                               unsigned short* __restrict__ outB,
                                               const float* __restrict__ bias) {
    constexpr long LDA = (MODE == 0 || MODE == 2) ? 512 : 1024;
    constexpr int NK = K / 32;
    const int t = threadIdx.x;
    const int wave = t >> 6, lane = t & 63;
    const int waveM = wave >> 1, waveN = wave & 1;
    const int quad = lane >> 4, l16 = lane & 15;

    // XCD-bijective chunk swizzle (nwg % 8 == 0): each XCD owns a contiguous
    // m-range for all n -> A-panel fetched once, shared in its L2.
    const int nwg = gridDim.x * gridDim.y;
    const int lid = blockIdx.y * gridDim.x + blockIdx.x;
    const int sid = (lid & 7) * (nwg >> 3) + (lid >> 3);
    const int nb = sid % gridDim.x;
    const int mb = sid / gridDim.x;
    const long n0 = (long)nb * 128;
    const long m0 = (long)mb * 128;

    __shared__ unsigned short lA[3][128 * 32];
    __shared__ unsigned short lB[3][128 * 32];

    f32x4 acc[4][4] = {};

    const int sRow = wave * 16 + (lane >> 2);            // 0..63
    const int sC = (lane & 3) ^ ((sRow >> 1) & 3);       // swizzled source chunk
    const unsigned short* Ag0 = A + (m0 + sRow) * LDA + sC * 8;
    const unsigned short* Ag1 = Ag0 + 64 * LDA;
    const unsigned short* Bg0 = Bt + (n0 + sRow) * (long)K + sC * 8;
    const unsigned short* Bg1 = Bg0 + 64 * (long)K;
    const int so0 = wave * 512;
    const int so1 = 2048 + wave * 512;

    const int sx = (l16 >> 1) & 3;
    int aoff[4], boff[4];
#pragma unroll
    for (int i = 0; i < 4; i++) {
        aoff[i] = (waveM * 64 + i * 16 + l16) * 32 + ((quad ^ sx) * 8);
        boff[i] = (waveN * 64 + i * 16 + l16) * 32 + ((quad ^ sx) * 8);
    }

#define STAGE(BUF, KT) do {                                   \
        async16(Ag0 + (KT) * 32, &lA[BUF][so0]);              \
        async16(Ag1 + (KT) * 32, &lA[BUF][so1]);              \
        async16(Bg0 + (KT) * 32, &lB[BUF][so0]);              \
        async16(Bg1 + (KT) * 32, &lB[BUF][so1]);              \
    } while (0)

    STAGE(0, 0);
    STAGE(1, 1);
    asm volatile("s_waitcnt vmcnt(4)" ::: "memory");
    __builtin_amdgcn_s_barrier();
    __builtin_amdgcn_sched_barrier(0);

#pragma unroll
    for (int kt = 0; kt < NK; ++kt) {
        if (kt + 2 < NK) {
            STAGE((kt + 2) % 3, kt + 2);
            __builtin_amdgcn_sched_barrier(0);
        }
        compute_tile(&lA[kt % 3][0], &lB[kt % 3][0], aoff, boff, acc);
        if (kt + 2 < NK) {
            asm volatile("s_waitcnt vmcnt(4) lgkmcnt(0)" ::: "memory");
            __builtin_amdgcn_s_barrier();
            __builtin_amdgcn_sched_barrier(0);
        } else if (kt + 1 < NK) {
            asm volatile("s_waitcnt vmcnt(0) lgkmcnt(0)" ::: "memory");
            __builtin_amdgcn_s_barrier();
            __builtin_amdgcn_sched_barrier(0);
        }
    }
#undef STAGE

#pragma unroll
    for (int i = 0; i < 4; i++) {
#pragma unroll
        for (int j = 0; j < 4; j++) {
            long col = n0 + waveN * 64 + j * 16 + l16;
            float bval = (MODE == 2 || MODE == 3) ? bias[col] : 0.f;
#pragma unroll
            for (int r = 0; r < 4; r++) {
                long row = m0 + waveM * 64 + i * 16 + quad * 4 + r;
                float v = acc[i][j][r];
                if (MODE == 1) {
                    long o = row * 512 + 256 + col;
                    outF[o] = v;
                    outB[o] = f2bf(v);
                } else if (MODE == 2) {
                    float z = v + bval;
                    float s = 1.f / (1.f + __expf(-z));
                    outB[row * 1024 + col] = f2bf(z * s);   // silu
                } else {
                    float z = v + bval;
                    outF[row * 256 + col] = 1.f / (1.f + __expf(-z));  // sigmoid
                }
            }
        }
    }
}

// ---------------- final memory blend + batch mean ----------------
// new_memory[m,c] = mem[m,c] + (1/64) * sum_b gate[b,m,c]*(xmean[b,c]-mem[m,c])
__global__ __launch_bounds__(256) void reduce_mem(const float* __restrict__ gate,
                                                  const float* __restrict__ memory,
                                                  const float* __restrict__ xmean,
                                                  float* __restrict__ out2) {
    int m = blockIdx.x, c = threadIdx.x;
    float mm = memory[m * 256 + c];
    float s = 0.f;
    for (int b = 0; b < 64; b++)
        s += gate[((long)(b * 1024 + m)) * 256 + c] * (xmean[b * 256 + c] - mm);
    out2[m * 256 + c] = mm + s * (1.f / 64.f);
}

extern "C" void kernel_launch(void* const* d_in, const int* in_sizes, int n_in,
                              void* d_out, int out_size, void* d_ws, size_t ws_size,
                              hipStream_t stream) {
    const float* x      = (const float*)d_in[0];
    const float* memory = (const float*)d_in[1];
    const float* w1     = (const float*)d_in[2];
    const float* b1     = (const float*)d_in[3];
    const float* w2     = (const float*)d_in[4];
    const float* b2     = (const float*)d_in[5];
    float* out = (float*)d_out;

    // workspace carve (all 16B aligned); peak ~194.6 MiB
    unsigned short* mem_b  = (unsigned short*)d_ws;            // 262144 el
    unsigned short* memT_b = mem_b + 262144;                   // 262144 el
    unsigned short* w1T    = memT_b + 262144;                  // 524288 el
    unsigned short* w2T    = w1T + 524288;                     // 262144 el
    float* xmean           = (float*)(w2T + 262144);           // 16384 el
    unsigned short* cat_b  = (unsigned short*)(xmean + 16384); // BT x 512
    unsigned short* Pbuf   = cat_b + 33554432;                 // BT x 1024; reused as h
    float* gate            = (float*)cat_b;                    // aliases cat_b (dead after GEMM2)

    hipMemsetAsync(xmean, 0, 64 * 256 * sizeof(float), stream);

    prep_mem<<<1024, 256, 0, stream>>>(memory, mem_b, memT_b);
    prep_w1<<<2048, 256, 0, stream>>>(w1, w1T);
    prep_w2<<<1024, 256, 0, stream>>>(w2, w2T);
    prep_x<<<16384, 256, 0, stream>>>(x, out, cat_b);
    xmean_k<<<dim3(64, 16), 256, 0, stream>>>(x, xmean);

    // P = softmax(x @ mem^T)  (fused energy + softmax)
    attn_es<<<1024, 512, 0, stream>>>(cat_b, mem_b, Pbuf);
    // retrieved = P @ mem : A=Pbuf (LDA=1024, K=1024), Bt=memT[256][1024]
    gemm_bt<1, 1024><<<dim3(2, 512), 256, 0, stream>>>(Pbuf, memT_b, out, cat_b, nullptr);
    // h = silu(cat@w1+b1) : A=cat_b (LDA=512, K=512), Bt=w1T[1024][512]
    gemm_bt<2, 512><<<dim3(8, 512), 256, 0, stream>>>(cat_b, w1T, nullptr, Pbuf, b1);
    // gate = sigmoid(h@w2+b2) : A=Pbuf/h (LDA=1024, K=1024), Bt=w2T[256][1024]
    gemm_bt<3, 1024><<<dim3(2, 512), 256, 0, stream>>>(Pbuf, w2T, gate, nullptr, b2);

    reduce_mem<<<1024, 256, 0, stream>>>(gate, memory, xmean, out + 33554432);
}